// Round 1
// baseline (90.680 us; speedup 1.0000x reference)
//
#include <hip/hip_runtime.h>

#define NROW 128   // DTW block size N
#define NCH  64    // channels
#define DSTR 66    // fp16 LDS stride for D (pad +2: anti-diagonal reads 2-way = free)
#define LOG2E  1.4426950408889634f
#define LN2    0.6931471805599453f
#define INFV   1e30f

typedef _Float16 h16;
typedef __attribute__((ext_vector_type(2))) _Float16 h16x2;

__device__ __forceinline__ float fdot2f(h16x2 a, h16x2 b, float c) {
#if __has_builtin(__builtin_amdgcn_fdot2)
    return __builtin_amdgcn_fdot2(a, b, c, false);
#else
    return c + (float)a[0] * (float)b[0] + (float)a[1] * (float)b[1];
#endif
}

__device__ __forceinline__ float ex2(float x) {
#if __has_builtin(__builtin_amdgcn_exp2f)
    return __builtin_amdgcn_exp2f(x);
#else
    return exp2f(x);
#endif
}

__device__ __forceinline__ float lg2(float x) {
#if __has_builtin(__builtin_amdgcn_logf)
    return __builtin_amdgcn_logf(x);   // v_log_f32 = log2
#else
    return log2f(x);
#endif
}

// One DP cell in log2 domain. Inputs are Rb = R*log2(e); returns Rb_new.
// Rb_new = K*D + m - log2( 2^(m-lf) + 2^(m-up) + 2^(m-dg) ),  m = min3
__device__ __forceinline__ float step_cell(float lf, float up, float dg, float Dv) {
    float m = fminf(fminf(lf, up), dg);
    float s = ex2(m - lf) + ex2(m - up) + ex2(m - dg);
    return fmaf(Dv, LOG2E, m - lg2(s));
}

__global__ __launch_bounds__(128, 2)
void dtw_k(const float* __restrict__ X, const float* __restrict__ Y,
           float* __restrict__ out, int nb_per_batch)
{
    __shared__ h16   sx[NROW * NCH];    // x block, fp16, XOR-swizzled 16B units
    __shared__ h16   sD[NROW * DSTR];   // cost matrix, fp16
    __shared__ float sx2[NROW];         // row squared norms of x

    const int w  = blockIdx.x;          // block-pair id, 0..1023
    const int lt = threadIdx.x;         // 0..127
    const float* gx = X + (size_t)w * (NROW * NCH);
    const float* gy = Y + (size_t)w * (NROW * NCH);

    // ---- own y row (lane = D column lt) -> fp16 regs; y2 in f32 ----
    h16x2 yr[32];
    #pragma unroll
    for (int u = 0; u < 8; ++u) {
        float4 a = *reinterpret_cast<const float4*>(gy + lt * NCH + u * 8);
        float4 b = *reinterpret_cast<const float4*>(gy + lt * NCH + u * 8 + 4);
        yr[u*4+0] = h16x2{(h16)a.x, (h16)a.y};
        yr[u*4+1] = h16x2{(h16)a.z, (h16)a.w};
        yr[u*4+2] = h16x2{(h16)b.x, (h16)b.y};
        yr[u*4+3] = h16x2{(h16)b.z, (h16)b.w};
    }
    float y2;
    {
        float c0=0.f, c1=0.f, c2=0.f, c3=0.f;
        #pragma unroll
        for (int k = 0; k < 32; k += 4) {
            c0 = fdot2f(yr[k+0], yr[k+0], c0);
            c1 = fdot2f(yr[k+1], yr[k+1], c1);
            c2 = fdot2f(yr[k+2], yr[k+2], c2);
            c3 = fdot2f(yr[k+3], yr[k+3], c3);
        }
        y2 = (c0+c1)+(c2+c3);
    }

    // ---- stage x block to LDS fp16, 16B-unit XOR swizzle (u ^ (row&7)) ----
    {
        const int u = lt & 7, sub = lt >> 3;   // 8 units x 16 rows per iter
        #pragma unroll
        for (int r0 = 0; r0 < NROW; r0 += 16) {
            int row = r0 + sub;
            float4 a = *reinterpret_cast<const float4*>(gx + row * NCH + u * 8);
            float4 b = *reinterpret_cast<const float4*>(gx + row * NCH + u * 8 + 4);
            h16x2 h[4] = { h16x2{(h16)a.x,(h16)a.y}, h16x2{(h16)a.z,(h16)a.w},
                           h16x2{(h16)b.x,(h16)b.y}, h16x2{(h16)b.z,(h16)b.w} };
            int su = (u ^ (row & 7)) * 8;
            *reinterpret_cast<float4*>(&sx[row * NCH + su]) =
                *reinterpret_cast<const float4*>(h);
        }
    }
    __syncthreads();

    // ---- x2 per row (lane lt handles row lt) ----
    {
        const int sw = lt & 7;
        float c0=0.f, c1=0.f, c2=0.f, c3=0.f;
        #pragma unroll
        for (int u = 0; u < 8; ++u) {
            float4 xf = *reinterpret_cast<const float4*>(&sx[lt * NCH + ((u ^ sw) * 8)]);
            h16x2 x0 = __builtin_bit_cast(h16x2, xf.x);
            h16x2 x1 = __builtin_bit_cast(h16x2, xf.y);
            h16x2 x2h= __builtin_bit_cast(h16x2, xf.z);
            h16x2 x3 = __builtin_bit_cast(h16x2, xf.w);
            c0 = fdot2f(x0,x0,c0); c1 = fdot2f(x1,x1,c1);
            c2 = fdot2f(x2h,x2h,c2); c3 = fdot2f(x3,x3,c3);
        }
        sx2[lt] = (c0+c1)+(c2+c3);
    }
    __syncthreads();

    // ---- D phase: lane owns column j = lt; loop rows i ----
    for (int i = 0; i < NROW; ++i) {
        const int sw = i & 7;
        float c0=0.f, c1=0.f, c2=0.f, c3=0.f;
        #pragma unroll
        for (int u = 0; u < 8; ++u) {
            float4 xf = *reinterpret_cast<const float4*>(&sx[i * NCH + ((u ^ sw) * 8)]);
            h16x2 x0 = __builtin_bit_cast(h16x2, xf.x);
            h16x2 x1 = __builtin_bit_cast(h16x2, xf.y);
            h16x2 x2h= __builtin_bit_cast(h16x2, xf.z);
            h16x2 x3 = __builtin_bit_cast(h16x2, xf.w);
            c0 = fdot2f(x0,  yr[u*4+0], c0);
            c1 = fdot2f(x1,  yr[u*4+1], c1);
            c2 = fdot2f(x2h, yr[u*4+2], c2);
            c3 = fdot2f(x3,  yr[u*4+3], c3);
        }
        float dot = (c0+c1)+(c2+c3);
        float Dv  = sx2[i] + y2 - 2.f * dot;
        sD[i * DSTR + lt] = (h16)Dv;
    }
    __syncthreads();

    // ---- DP anti-diagonal wavefront: wave 0 only, lane t owns rows 2t, 2t+1 ----
    if (lt >= 64) return;
    const int t = lt;
    const h16* pD0 = &sD[(2*t)     * DSTR];
    const h16* pD1 = &sD[(2*t + 1) * DSTR];

    // r1* = value at diagonal d-1, r2* = at d-2; a = row 2t (slot0), b = row 2t+1
    float r1a = INFV, r1b = INFV, r2a = INFV, r2b = INFV;

    for (int d = 0; d < 2*NROW - 1; ++d) {
        // slot0 (row 2t, col j0=d-2t): up/diag come from row 2t-1 = slot1 of lane t-1
        float up0 = __shfl_up(r1b, 1, 64);
        float dg0 = __shfl_up(r2b, 1, 64);
        if (t == 0) { up0 = INFV; dg0 = (d == 0) ? 0.f : INFV; }  // row -1; corner R[-1][-1]=0

        const int j0 = d - 2*t;
        const int j1 = j0 - 1;
        const int cj0 = j0 < 0 ? 0 : (j0 > NROW-1 ? NROW-1 : j0);
        const int cj1 = j1 < 0 ? 0 : (j1 > NROW-1 ? NROW-1 : j1);
        const float D0 = (float)pD0[cj0];
        const float D1 = (float)pD1[cj1];

        // slot1 (row 2t+1): up = row 2t same col  -> old r1a
        //                   diag = row 2t col-1   -> old r2a ; left = old r1b
        float n0 = step_cell(r1a, up0, dg0, D0);
        float n1 = step_cell(r1b, r1a, r2a, D1);

        r2a = r1a;
        r1a = (j0 >= 0 && j0 < NROW) ? n0 : INFV;
        r2b = r1b;
        r1b = (j1 >= 0 && j1 < NROW) ? n1 : INFV;
    }

    // Rb[127][127] sits in r1b of lane 63; convert back from log2 domain, sum per batch
    if (t == 63) {
        atomicAdd(&out[w / nb_per_batch], r1b * LN2);
    }
}

extern "C" void kernel_launch(void* const* d_in, const int* in_sizes, int n_in,
                              void* d_out, int out_size, void* d_ws, size_t ws_size,
                              hipStream_t stream) {
    const float* x = (const float*)d_in[0];
    const float* y = (const float*)d_in[1];
    float* out = (float*)d_out;

    const int nblk = in_sizes[0] / (NROW * NCH);   // total block-pairs (1024)
    const int nbpb = nblk / out_size;              // blocks per batch (32)

    hipMemsetAsync(out, 0, (size_t)out_size * sizeof(float), stream);
    dtw_k<<<nblk, 128, 0, stream>>>(x, y, out, nbpb);
}

// Round 2
// 68.177 us; speedup vs baseline: 1.3301x; 1.3301x over previous
//
#include <hip/hip_runtime.h>

#define NB   128            // DTW block size N
#define NCH  64             // channels
#define SD   130            // sD stride in h16 (128 cols + 2 pad) -> DP windows 4B-aligned, 2-way banks
#define LOG2E 1.4426950408889634f
#define LN2   0.6931471805599453f
#define LARGE 1e9f

typedef _Float16 h16;
typedef __attribute__((ext_vector_type(2))) _Float16 h16x2;
typedef __attribute__((ext_vector_type(8))) _Float16 h16x8;

static __device__ __forceinline__ float fdot2f(h16x2 a, h16x2 b, float c) {
#if __has_builtin(__builtin_amdgcn_fdot2)
    return __builtin_amdgcn_fdot2(a, b, c, false);
#else
    return c + (float)a[0] * (float)b[0] + (float)a[1] * (float)b[1];
#endif
}

static __device__ __forceinline__ float ex2(float x) {
#if __has_builtin(__builtin_amdgcn_exp2f)
    return __builtin_amdgcn_exp2f(x);
#else
    return exp2f(x);
#endif
}

static __device__ __forceinline__ float lg2(float x) {
#if __has_builtin(__builtin_amdgcn_logf)
    return __builtin_amdgcn_logf(x);   // v_log_f32 = log2
#else
    return log2f(x);
#endif
}

// lane t gets lane t-1's src; lane 0 gets `fill`. Pure VALU (DPP wave_shr:1), no LDS.
static __device__ __forceinline__ float shift_up1(float src, float fill) {
    int r = __builtin_amdgcn_update_dpp(__builtin_bit_cast(int, fill),
                                        __builtin_bit_cast(int, src),
                                        0x138 /*wave_shr:1*/, 0xf, 0xf, false);
    return __builtin_bit_cast(float, r);
}

// soft-min of 3 in log2 domain + D*log2e. Exactly -gamma*lse(-r/gamma)*log2e with gamma=1.
// Only the two non-min terms need exp2 (min term is exp2(0)=1).
static __device__ __forceinline__ float softmin3(float a, float b, float c, float Dv) {
    float m = fminf(fminf(a, b), c);
    float M = fmaxf(fmaxf(a, b), c);
#if __has_builtin(__builtin_amdgcn_fmed3f)
    float e = __builtin_amdgcn_fmed3f(a, b, c);
#else
    float e = ((a + b) + c) - m - M;
#endif
    float s = 1.0f + (ex2(m - e) + ex2(m - M));
    return fmaf(Dv, LOG2E, m - lg2(s));
}

__global__ __launch_bounds__(64, 1)
void dtw_k(const float* __restrict__ X, const float* __restrict__ Y,
           float* __restrict__ out, int nbpb)
{
    // D matrix fp16, stride 130. x rows are OVERLAID inside sD rows (16B-aligned
    // offset within each 260B row); D row i overwrites x row i only after its
    // single use at iteration i. Single wave -> in-order DS pipe, no barriers.
    __shared__ h16   sD[NB * SD];     // 33280 B
    __shared__ float sx2[NB];         // 512 B  -> total 33792 B -> 4 wgs/CU

    const int w = blockIdx.x;         // block-pair id
    const int t = threadIdx.x;        // 0..63
    char* sDb = (char*)sD;
    const float* gx = X + (size_t)w * (NB * NCH);
    const float* gy = Y + (size_t)w * (NB * NCH);

    // ---- zero pad words (h16 cols 128,129 of each row): keeps OOW DP reads finite >=0
    *(unsigned*)(sDb + 260 * (2 * t)     + 256) = 0u;
    *(unsigned*)(sDb + 260 * (2 * t + 1) + 256) = 0u;

    // ---- y rows {2t, 2t+1} -> fp16 regs (these are D columns 2t, 2t+1); y2 in f32
    h16x2 y0[32], y1[32];
    float y20, y21;
    {
        const float4* gy0 = (const float4*)(gy + (2 * t) * NCH);
        const float4* gy1 = (const float4*)(gy + (2 * t + 1) * NCH);
        float a0=0.f,a1=0.f,a2=0.f,a3=0.f, b0=0.f,b1=0.f,b2=0.f,b3=0.f;
        #pragma unroll
        for (int u = 0; u < 16; ++u) {
            float4 v = gy0[u];
            y0[2*u]   = h16x2{(h16)v.x, (h16)v.y};
            y0[2*u+1] = h16x2{(h16)v.z, (h16)v.w};
            a0=fmaf(v.x,v.x,a0); a1=fmaf(v.y,v.y,a1);
            a2=fmaf(v.z,v.z,a2); a3=fmaf(v.w,v.w,a3);
            float4 q = gy1[u];
            y1[2*u]   = h16x2{(h16)q.x, (h16)q.y};
            y1[2*u+1] = h16x2{(h16)q.z, (h16)q.w};
            b0=fmaf(q.x,q.x,b0); b1=fmaf(q.y,q.y,b1);
            b2=fmaf(q.z,q.z,b2); b3=fmaf(q.w,q.w,b3);
        }
        y20 = (a0+a1)+(a2+a3);
        y21 = (b0+b1)+(b2+b3);
    }

    // ---- x rows {2t, 2t+1}: x2 -> sx2 (f32), fp16 row -> overlay inside sD row
    #pragma unroll
    for (int rr = 0; rr < 2; ++rr) {
        const int row = 2 * t + rr;
        const float4* gxr = (const float4*)(gx + row * NCH);
        h16x8* dst = (h16x8*)(sDb + ((260 * row + 15) & ~15));
        float a0=0.f,a1=0.f,a2=0.f,a3=0.f;
        #pragma unroll
        for (int u = 0; u < 8; ++u) {
            float4 v = gxr[2*u];
            float4 q = gxr[2*u+1];
            h16x8 h;
            h[0]=(h16)v.x; h[1]=(h16)v.y; h[2]=(h16)v.z; h[3]=(h16)v.w;
            h[4]=(h16)q.x; h[5]=(h16)q.y; h[6]=(h16)q.z; h[7]=(h16)q.w;
            dst[u] = h;
            a0=fmaf(v.x,v.x,a0); a1=fmaf(v.y,v.y,a1);
            a2=fmaf(v.z,v.z,a2); a3=fmaf(v.w,v.w,a3);
            a0=fmaf(q.x,q.x,a0); a1=fmaf(q.y,q.y,a1);
            a2=fmaf(q.z,q.z,a2); a3=fmaf(q.w,q.w,a3);
        }
        sx2[row] = (a0+a1)+(a2+a3);
    }

    // ---- D phase: lane owns columns {2t, 2t+1}; rows broadcast from LDS, double-buffered
    float4 bufA[8], bufB[8];
    {
        const float4* p = (const float4*)(sDb + 15 /*row 0 aligned base: (0+15)&~15 = 0*/);
        (void)p;
    }
    #define LOADROW(buf, ri) { \
        const float4* xp = (const float4*)(sDb + ((260 * (ri) + 15) & ~15)); \
        _Pragma("unroll") for (int u = 0; u < 8; ++u) (buf)[u] = xp[u]; }
    #define DROW(buf, ri) { \
        float c0=0.f,c1=0.f,c2=0.f,c3=0.f; \
        _Pragma("unroll") for (int u = 0; u < 8; ++u) { \
            h16x2 x0 = __builtin_bit_cast(h16x2, (buf)[u].x); \
            h16x2 x1 = __builtin_bit_cast(h16x2, (buf)[u].y); \
            h16x2 x2 = __builtin_bit_cast(h16x2, (buf)[u].z); \
            h16x2 x3 = __builtin_bit_cast(h16x2, (buf)[u].w); \
            c0 = fdot2f(x0, y0[4*u+0], c0); c1 = fdot2f(x1, y0[4*u+1], c1); \
            c0 = fdot2f(x2, y0[4*u+2], c0); c1 = fdot2f(x3, y0[4*u+3], c1); \
            c2 = fdot2f(x0, y1[4*u+0], c2); c3 = fdot2f(x1, y1[4*u+1], c3); \
            c2 = fdot2f(x2, y1[4*u+2], c2); c3 = fdot2f(x3, y1[4*u+3], c3); \
        } \
        float x2i = sx2[(ri)]; \
        float D0 = x2i + y20 - 2.0f * (c0 + c1); \
        float D1 = x2i + y21 - 2.0f * (c2 + c3); \
        *(h16x2*)(sDb + 260 * (ri) + 4 * t) = h16x2{(h16)D0, (h16)D1}; }

    LOADROW(bufA, 0)
    for (int i = 0; i < NB; i += 2) {
        LOADROW(bufB, i + 1)            // prefetch before consuming/writing row i
        DROW(bufA, i)
        const int i2 = (i + 2 < NB) ? (i + 2) : (NB - 1);
        LOADROW(bufA, i2)
        DROW(bufB, i + 1)
    }

    // ---- DP wavefront: lane t owns rows 2t (state a) and 2t+1 (state b)
    // log2-domain R~ = R*log2e. One DPP shift/step; dg(d) = up(d-1) carried.
    // No validity masks: pads are 0, all OOW D reads finite>=0 => junk stays ~1e9.
    // Window for chunk c (steps d=16c..16c+15): j0 = 16c + k - 2t.
    // rowA bytes: 516t + 32c + 4q ; rowB: 516t + 260 + 32c + 4q  (both 4B-aligned)
    const int baseA = 516 * t;
    const int baseB = 516 * t + 260;

    h16x2 nA[8], nB[8];
    #define LOAD8(dst, off) { \
        const h16x2* p = (const h16x2*)(sDb + (off)); \
        _Pragma("unroll") for (int q = 0; q < 8; ++q) (dst)[q] = p[q]; }

    LOAD8(nA, baseA)
    LOAD8(nB, baseB)

    float fA[16], fB[16];
    float r1a = LARGE, r1b = LARGE, r2a = LARGE;
    float dg_prev = (t == 0) ? 0.0f : LARGE;   // corner R[-1][-1]=0 feeds cell (0,0) at d=0
    float carryB = 0.0f;                        // D1 for k=0 of chunk 0 (always invalid cell)

    #define CONVERT() { _Pragma("unroll") for (int q = 0; q < 8; ++q) { \
        fA[2*q] = (float)nA[q][0]; fA[2*q+1] = (float)nA[q][1]; \
        fB[2*q] = (float)nB[q][0]; fB[2*q+1] = (float)nB[q][1]; } }

    #define STEP(D0v, D1v) { \
        float up_cur = shift_up1(r1b, LARGE); \
        float n0 = softmin3(r1a, up_cur, dg_prev, (D0v)); \
        float n1 = softmin3(r1b, r1a, r2a, (D1v)); \
        r2a = r1a; r1a = n0; r1b = n1; dg_prev = up_cur; }

    for (int c = 0; c < 15; ++c) {
        CONVERT()
        LOAD8(nA, baseA + 32 * (c + 1))
        LOAD8(nB, baseB + 32 * (c + 1))
        #pragma unroll
        for (int k = 0; k < 16; ++k) {
            float D1v = (k == 0) ? carryB : fB[k - 1];
            STEP(fA[k], D1v)
        }
        carryB = fB[15];
    }
    CONVERT()
    #pragma unroll
    for (int k = 0; k < 15; ++k) {     // d = 240..254; stop at 254 so lane63 r1b = R~[127][127]
        float D1v = (k == 0) ? carryB : fB[k - 1];
        STEP(fA[k], D1v)
    }

    if (t == 63) {
        atomicAdd(&out[w / nbpb], r1b * LN2);   // back to natural-log domain
    }
}

extern "C" void kernel_launch(void* const* d_in, const int* in_sizes, int n_in,
                              void* d_out, int out_size, void* d_ws, size_t ws_size,
                              hipStream_t stream) {
    const float* x = (const float*)d_in[0];
    const float* y = (const float*)d_in[1];
    float* out = (float*)d_out;

    const int nblk = in_sizes[0] / (NB * NCH);   // 1024 block-pairs
    const int nbpb = nblk / out_size;            // 32 blocks per batch

    hipMemsetAsync(out, 0, (size_t)out_size * sizeof(float), stream);
    dtw_k<<<nblk, 64, 0, stream>>>(x, y, out, nbpb);
}

// Round 3
// 42.755 us; speedup vs baseline: 2.1209x; 1.5946x over previous
//
#include <hip/hip_runtime.h>

#define NB    128           // DTW block size N
#define NCH   64            // channels
#define ROWB  260           // bytes per sD row: 128 h16 + 2 pad h16
#define LOG2E 1.4426950408889634f
#define LN2   0.6931471805599453f
#define LARGE 1e9f

typedef _Float16 h16;
typedef __attribute__((ext_vector_type(2))) _Float16 h16x2;
typedef __attribute__((ext_vector_type(8))) _Float16 h16x8;
typedef __attribute__((ext_vector_type(4))) float    f32x4;

static __device__ __forceinline__ float ex2(float x) {
#if __has_builtin(__builtin_amdgcn_exp2f)
    return __builtin_amdgcn_exp2f(x);
#else
    return exp2f(x);
#endif
}

static __device__ __forceinline__ float lg2(float x) {
#if __has_builtin(__builtin_amdgcn_logf)
    return __builtin_amdgcn_logf(x);   // v_log_f32 = log2
#else
    return log2f(x);
#endif
}

// lane t gets lane t-1's src; lane 0 gets `fill`. Pure VALU (DPP wave_shr:1).
static __device__ __forceinline__ float shift_up1(float src, float fill) {
    int r = __builtin_amdgcn_update_dpp(__builtin_bit_cast(int, fill),
                                        __builtin_bit_cast(int, src),
                                        0x138 /*wave_shr:1*/, 0xf, 0xf, false);
    return __builtin_bit_cast(float, r);
}

// soft-min of 3 in log2 domain + D*log2e (gamma=1, exact w.r.t. reference).
static __device__ __forceinline__ float softmin3(float a, float b, float c, float Dv) {
    float m = fminf(fminf(a, b), c);
    float M = fmaxf(fmaxf(a, b), c);
#if __has_builtin(__builtin_amdgcn_fmed3f)
    float e = __builtin_amdgcn_fmed3f(a, b, c);
#else
    float e = ((a + b) + c) - m - M;
#endif
    float s = 1.0f + (ex2(m - e) + ex2(m - M));
    return fmaf(Dv, LOG2E, m - lg2(s));
}

__global__ __launch_bounds__(64, 1)
void dtw_k(const float* __restrict__ X, const float* __restrict__ Y,
           float* __restrict__ out, int nbpb)
{
    __shared__ h16   sD[NB * (ROWB / 2)];   // 33280 B, D row-major fp16, stride 260 B
    __shared__ float sx2[NB];               // 512 B  -> total 33792 B -> 4 wgs/CU

    const int w = blockIdx.x;               // block-pair id
    const int t = threadIdx.x;              // 0..63
    const int c = t & 15, g = t >> 4;       // MFMA fragment coords
    char* sDb = (char*)sD;
    const float* gx = X + (size_t)w * (NB * NCH);
    const float* gy = Y + (size_t)w * (NB * NCH);

    // ---- zero pad words (h16 cols 128,129): keeps OOW DP reads finite >= 0
    *(unsigned*)(sDb + ROWB * (2 * t)     + 256) = 0u;
    *(unsigned*)(sDb + ROWB * (2 * t + 1) + 256) = 0u;

    // ---- B fragments (y rows as MFMA B operand) + y2 norms, all in registers.
    // Lane l holds y[16J + (l&15)][32q + 8*(l>>4) .. +8] for mfma_f32_16x16x32_f16.
    h16x8 Bf[8][2];
    float y2r[8];
    #pragma unroll
    for (int J = 0; J < 8; ++J) {
        const float* py = gy + (16 * J + c) * NCH + 8 * g;
        float p = 0.f;
        #pragma unroll
        for (int q = 0; q < 2; ++q) {
            float4 a = *(const float4*)(py + 32 * q);
            float4 b = *(const float4*)(py + 32 * q + 4);
            h16x8 h;
            h[0]=(h16)a.x; h[1]=(h16)a.y; h[2]=(h16)a.z; h[3]=(h16)a.w;
            h[4]=(h16)b.x; h[5]=(h16)b.y; h[6]=(h16)b.z; h[7]=(h16)b.w;
            Bf[J][q] = h;
            p = fmaf(a.x,a.x,p); p = fmaf(a.y,a.y,p);
            p = fmaf(a.z,a.z,p); p = fmaf(a.w,a.w,p);
            p = fmaf(b.x,b.x,p); p = fmaf(b.y,b.y,p);
            p = fmaf(b.z,b.z,p); p = fmaf(b.w,b.w,p);
        }
        p += __shfl_xor(p, 16, 64);          // sum the 4 channel-octet groups
        p += __shfl_xor(p, 32, 64);
        y2r[J] = p;                          // ||y[16J+c]||^2, exactly what this lane needs
    }

    // ---- D phase: 8 row-tiles of 16; A frags prefetched one tile ahead
    float4 nx0, nx1, nx2, nx3;               // raw f32 A data for next I
    {
        const float* px = gx + c * NCH + 8 * g;
        nx0 = *(const float4*)(px);
        nx1 = *(const float4*)(px + 4);
        nx2 = *(const float4*)(px + 32);
        nx3 = *(const float4*)(px + 36);
    }
    for (int I = 0; I < 8; ++I) {
        float4 a0 = nx0, a1 = nx1, a2 = nx2, a3 = nx3;
        if (I < 7) {
            const float* px = gx + (16 * (I + 1) + c) * NCH + 8 * g;
            nx0 = *(const float4*)(px);
            nx1 = *(const float4*)(px + 4);
            nx2 = *(const float4*)(px + 32);
            nx3 = *(const float4*)(px + 36);
        }
        // pack A frags + x2 partial
        h16x8 Af0, Af1;
        Af0[0]=(h16)a0.x; Af0[1]=(h16)a0.y; Af0[2]=(h16)a0.z; Af0[3]=(h16)a0.w;
        Af0[4]=(h16)a1.x; Af0[5]=(h16)a1.y; Af0[6]=(h16)a1.z; Af0[7]=(h16)a1.w;
        Af1[0]=(h16)a2.x; Af1[1]=(h16)a2.y; Af1[2]=(h16)a2.z; Af1[3]=(h16)a2.w;
        Af1[4]=(h16)a3.x; Af1[5]=(h16)a3.y; Af1[6]=(h16)a3.z; Af1[7]=(h16)a3.w;
        float p = 0.f;
        p = fmaf(a0.x,a0.x,p); p = fmaf(a0.y,a0.y,p); p = fmaf(a0.z,a0.z,p); p = fmaf(a0.w,a0.w,p);
        p = fmaf(a1.x,a1.x,p); p = fmaf(a1.y,a1.y,p); p = fmaf(a1.z,a1.z,p); p = fmaf(a1.w,a1.w,p);
        p = fmaf(a2.x,a2.x,p); p = fmaf(a2.y,a2.y,p); p = fmaf(a2.z,a2.z,p); p = fmaf(a2.w,a2.w,p);
        p = fmaf(a3.x,a3.x,p); p = fmaf(a3.y,a3.y,p); p = fmaf(a3.z,a3.z,p); p = fmaf(a3.w,a3.w,p);
        p += __shfl_xor(p, 16, 64);
        p += __shfl_xor(p, 32, 64);
        sx2[16 * I + c] = p;                 // ||x[16I+c]||^2 (4 dup lanes, same value)

        // 16 MFMAs: acc[J] = x_tile(I) . y_tile(J)^T
        f32x4 acc[8];
        #pragma unroll
        for (int J = 0; J < 8; ++J) {
            f32x4 z = {0.f, 0.f, 0.f, 0.f};
            z = __builtin_amdgcn_mfma_f32_16x16x32_f16(Af0, Bf[J][0], z, 0, 0, 0);
            z = __builtin_amdgcn_mfma_f32_16x16x32_f16(Af1, Bf[J][1], z, 0, 0, 0);
            acc[J] = z;
        }

        // epilogue: D[16I+4g+p][16J+c] = x2 + y2 - 2*dot  (C layout: col=l&15, row=4g+p)
        float4 x2v = *(const float4*)&sx2[16 * I + 4 * g];   // same-wave DS is in-order
        float xa[4] = {x2v.x, x2v.y, x2v.z, x2v.w};
        #pragma unroll
        for (int J = 0; J < 8; ++J) {
            char* base = sDb + 2 * (16 * J + c) + ROWB * (16 * I + 4 * g);
            float y2v = y2r[J];
            #pragma unroll
            for (int r = 0; r < 4; ++r) {
                float dv = fmaf(-2.0f, acc[J][r], xa[r] + y2v);
                *(h16*)(base + ROWB * r) = (h16)dv;
            }
        }
    }

    // ---- DP wavefront (verbatim from passing round-2 kernel) ----
    // lane t owns rows 2t (state a) and 2t+1 (state b); log2-domain R~ = R*log2e.
    // Chunk c covers steps d=16c..16c+15; fA[k] = D[2t][16c+k-2t] via base 516t = 520t - 4t.
    const int baseA = 516 * t;
    const int baseB = 516 * t + 260;

    h16x2 nA[8], nB[8];
    #define LOAD8(dst, off) { \
        const h16x2* p_ = (const h16x2*)(sDb + (off)); \
        _Pragma("unroll") for (int q = 0; q < 8; ++q) (dst)[q] = p_[q]; }

    LOAD8(nA, baseA)
    LOAD8(nB, baseB)

    float fA[16], fB[16];
    float r1a = LARGE, r1b = LARGE, r2a = LARGE;
    float dg_prev = (t == 0) ? 0.0f : LARGE;   // corner R[-1][-1]=0 feeds cell (0,0) at d=0
    float carryB = 0.0f;

    #define CONVERT() { _Pragma("unroll") for (int q = 0; q < 8; ++q) { \
        fA[2*q] = (float)nA[q][0]; fA[2*q+1] = (float)nA[q][1]; \
        fB[2*q] = (float)nB[q][0]; fB[2*q+1] = (float)nB[q][1]; } }

    #define STEP(D0v, D1v) { \
        float up_cur = shift_up1(r1b, LARGE); \
        float n0 = softmin3(r1a, up_cur, dg_prev, (D0v)); \
        float n1 = softmin3(r1b, r1a, r2a, (D1v)); \
        r2a = r1a; r1a = n0; r1b = n1; dg_prev = up_cur; }

    for (int cc = 0; cc < 15; ++cc) {
        CONVERT()
        LOAD8(nA, baseA + 32 * (cc + 1))
        LOAD8(nB, baseB + 32 * (cc + 1))
        #pragma unroll
        for (int k = 0; k < 16; ++k) {
            float D1v = (k == 0) ? carryB : fB[k - 1];
            STEP(fA[k], D1v)
        }
        carryB = fB[15];
    }
    CONVERT()
    #pragma unroll
    for (int k = 0; k < 15; ++k) {     // d = 240..254; lane63 r1b ends as R~[127][127]
        float D1v = (k == 0) ? carryB : fB[k - 1];
        STEP(fA[k], D1v)
    }

    if (t == 63) {
        atomicAdd(&out[w / nbpb], r1b * LN2);   // back to natural-log domain
    }
}

extern "C" void kernel_launch(void* const* d_in, const int* in_sizes, int n_in,
                              void* d_out, int out_size, void* d_ws, size_t ws_size,
                              hipStream_t stream) {
    const float* x = (const float*)d_in[0];
    const float* y = (const float*)d_in[1];
    float* out = (float*)d_out;

    const int nblk = in_sizes[0] / (NB * NCH);   // 1024 block-pairs
    const int nbpb = nblk / out_size;            // 32 blocks per batch

    hipMemsetAsync(out, 0, (size_t)out_size * sizeof(float), stream);
    dtw_k<<<nblk, 64, 0, stream>>>(x, y, out, nbpb);
}